// Round 8
// baseline (695.963 us; speedup 1.0000x reference)
//
#include <hip/hip_runtime.h>
#include <math.h>

#define NROWS 65536
#define KCODES 1024
#define DDIM 256
#define ND_TOT (NROWS * DDIM)

// ---------- ws layout (bytes) ----------
#define WS_IDX      0         // int idx[N]          256KB
#define WS_COUNTS   262144    // int counts[K]       4KB
#define WS_SW       266240    // float sw[K]         4KB
#define WS_PARTQ    532480    // float partQ[1024]   4KB
#define WS_PARTP    536576    // float partP[1024]   4KB
#define WS_FLAGCNT  540672    // int                 (256B slot)
#define WS_FLAGLIST 540928    // int flagList[N]     256KB
#define WS_WH       803072    // ushort wh[K*256]    512KB
#define WS_WL       1327360   // ushort wl[K*256]    512KB

typedef float f32x4 __attribute__((ext_vector_type(4)));
typedef short bf16x8 __attribute__((ext_vector_type(8)));

__device__ inline unsigned short f2bf(float f) {
  unsigned u = __float_as_uint(f);
  u += 0x7FFFu + ((u >> 16) & 1u);   // RNE to bf16
  return (unsigned short)(u >> 16);
}
__device__ inline float bf2f(unsigned short h) {
  return __uint_as_float(((unsigned)h) << 16);
}

__device__ inline void gload16(const void* g, void* l) {
  __builtin_amdgcn_global_load_lds((const __attribute__((address_space(1))) void*)g,
                                   (__attribute__((address_space(3))) void*)l, 16, 0, 0);
}

// ========== elementwise bf16 split of x (fully coalesced, grid-stride) ==========
__global__ __launch_bounds__(256) void vq_split_x(const float* __restrict__ x,
                                                  unsigned short* __restrict__ xh,
                                                  unsigned short* __restrict__ xl) {
  const size_t stride = (size_t)gridDim.x * 256;
  for (size_t i = (size_t)blockIdx.x * 256 + threadIdx.x; i < ND_TOT / 8; i += stride) {
    const size_t e = i * 8;
    float4 a = *(const float4*)&x[e];
    float4 b = *(const float4*)&x[e + 4];
    float fv[8] = {a.x, a.y, a.z, a.w, b.x, b.y, b.z, b.w};
    union { unsigned short us[8]; uint4 v; } ph, pl;
#pragma unroll
    for (int k = 0; k < 8; ++k) {
      unsigned short h = f2bf(fv[k]);
      ph.us[k] = h;
      pl.us[k] = f2bf(fv[k] - bf2f(h));   // exact in fp32
    }
    *(uint4*)&xh[e] = ph.v;
    *(uint4*)&xl[e] = pl.v;
  }
}

// ========== w prep: bf16 split + exact sw (numpy-pairwise, tiny) ==========
__global__ __launch_bounds__(128) void vq_prep_w(const float* __restrict__ w,
                                                 float* __restrict__ sw,
                                                 unsigned short* __restrict__ wh,
                                                 unsigned short* __restrict__ wl) {
#pragma clang fp contract(off)
  int k = blockIdx.x * 128 + threadIdx.x;
  if (k >= KCODES) return;
  const float* src = w + (size_t)k * DDIM;
  unsigned short* hdst = wh + (size_t)k * DDIM;
  unsigned short* ldst = wl + (size_t)k * DDIM;
  for (int i = 0; i < DDIM; i += 8) {
    float4 a = *(const float4*)&src[i];
    float4 b = *(const float4*)&src[i + 4];
    float fv[8] = {a.x, a.y, a.z, a.w, b.x, b.y, b.z, b.w};
    union { unsigned short us[8]; uint4 v; } ph, pl;
#pragma unroll
    for (int e = 0; e < 8; ++e) {
      unsigned short h = f2bf(fv[e]);
      ph.us[e] = h;
      pl.us[e] = f2bf(fv[e] - bf2f(h));
    }
    *(uint4*)&hdst[i] = ph.v;
    *(uint4*)&ldst[i] = pl.v;
  }
  float halves[2];
#pragma unroll
  for (int h = 0; h < 2; ++h) {
    const float* p = src + h * 128;
    float acc[8];
#pragma unroll
    for (int j = 0; j < 8; ++j) { float v = p[j]; acc[j] = v * v; }
    for (int i = 8; i < 128; i += 8) {
#pragma unroll
      for (int j = 0; j < 8; ++j) { float v = p[i + j]; float e = v * v; acc[j] = acc[j] + e; }
    }
    halves[h] = ((acc[0] + acc[1]) + (acc[2] + acc[3])) + ((acc[4] + acc[5]) + (acc[6] + acc[7]));
  }
  sw[k] = halves[0] + halves[1];
}

// ========== MFMA split-bf16 distance + top2 argmin ==========
// x-stationary: 128 rows' full D resident in LDS (staged once, XOR-swizzled).
// w read per-lane direct from global (2MB splits, L2-hot). NO barriers in main loop.
// j-half split keeps live VGPRs ~140 (R7 spilled at cap 128 from launch_bounds(512,2)).
#define TRM 128
// Flag threshold: hard bound for a reference-order flip is
//   approx-e error (<=~6e-6) + reference rounding reorder width (~6.1e-5).
// Total ~7.3e-5; T=1.5e-4 keeps 2x margin.
#define REPAIR_T 1.5e-4f

__global__ __launch_bounds__(512, 1) void vq_argmin_mfma(
    const unsigned short* __restrict__ xh, const unsigned short* __restrict__ xl,
    const unsigned short* __restrict__ wh, const unsigned short* __restrict__ wl,
    const float* __restrict__ sw,
    int* __restrict__ idxOut, float* __restrict__ idxOutF,
    int* __restrict__ flagCnt, int* __restrict__ flagList) {
  __shared__ __align__(16) unsigned short lds_xh[TRM * DDIM];  // 64KB, full-D, swizzled
  __shared__ __align__(16) unsigned short lds_xl[TRM * DDIM];  // 64KB
  __shared__ float mrgB1[TRM][4];
  __shared__ float mrgB2[TRM][4];
  __shared__ int   mrgI[TRM][4];

  const int t = threadIdx.x;                // 512 threads = 8 waves
  const int lane = t & 63, wv = t >> 6;
  const int wr = wv >> 2, wc = wv & 3;      // wave grid 2x4: rows 64*wr, cols 64*wc
  const int row0 = blockIdx.x * TRM;

  const char* xhB = (const char*)xh;
  const char* xlB = (const char*)xl;
  const char* whB = (const char*)wh;
  const char* wlB = (const char*)wl;

  // ---- one-time x staging: per wave 16 rows x 512B per array; 2 rows per gload16 instr ----
#pragma unroll
  for (int it = 0; it < 8; ++it) {
    const int rowl = wv * 16 + it * 2 + (lane >> 5);
    const int binrow = ((lane & 31) * 16) ^ ((rowl & 7) << 4);  // pre-swizzled source
    const size_t go = (size_t)(row0 + rowl) * 512 + (size_t)binrow;
    gload16(xhB + go, (char*)lds_xh + (wv * 16 + it * 2) * 512);
    gload16(xlB + go, (char*)lds_xl + (wv * 16 + it * 2) * 512);
  }
  __syncthreads();   // drains vmcnt; x LDS is read-only from here on

  float b1[16], b2[16];
  int bi[16];
#pragma unroll
  for (int s = 0; s < 16; ++s) { b1[s] = 3.4e38f; b2[s] = 3.4e38f; bi[s] = 0; }

  for (int ct = 0; ct < 4; ++ct) {          // 256 codes per iter
#pragma unroll
    for (int jh = 0; jh < 2; ++jh) {        // 2 column-halves of 32 codes: halves VGPR liveness
      f32x4 acc[4][2];
#pragma unroll
      for (int i = 0; i < 4; ++i)
#pragma unroll
        for (int j2 = 0; j2 < 2; ++j2) acc[i][j2] = (f32x4){0.f, 0.f, 0.f, 0.f};

#pragma unroll
      for (int dt = 0; dt < 4; ++dt) {
#pragma unroll
        for (int kh = 0; kh < 2; ++kh) {
          const int kb = dt * 128 + kh * 64 + ((lane >> 4) & 3) * 16;
          bf16x8 ah[4], al[4];
#pragma unroll
          for (int i = 0; i < 4; ++i) {
            const int r = wr * 64 + i * 16 + (lane & 15);
            const int off = r * 512 + (kb ^ ((r & 7) << 4));
            ah[i] = *(const bf16x8*)((const char*)lds_xh + off);
            al[i] = *(const bf16x8*)((const char*)lds_xl + off);
          }
#pragma unroll
          for (int j2 = 0; j2 < 2; ++j2) {
            const int c = ct * 256 + wc * 64 + (jh * 2 + j2) * 16 + (lane & 15);
            const size_t wo = (size_t)c * 512 + (size_t)kb;    // no swizzle: direct global
            bf16x8 bh = *(const bf16x8*)(whB + wo);
            bf16x8 bl = *(const bf16x8*)(wlB + wo);
#pragma unroll
            for (int i = 0; i < 4; ++i) {
              acc[i][j2] = __builtin_amdgcn_mfma_f32_16x16x32_bf16(ah[i], bh, acc[i][j2], 0, 0, 0);
              acc[i][j2] = __builtin_amdgcn_mfma_f32_16x16x32_bf16(ah[i], bl, acc[i][j2], 0, 0, 0);
              acc[i][j2] = __builtin_amdgcn_mfma_f32_16x16x32_bf16(al[i], bh, acc[i][j2], 0, 0, 0);
            }
          }
        }
      }

      // top-2 update in e-space: e = sw - 2*dot (sx drops out of per-row argmin)
#pragma unroll
      for (int j2 = 0; j2 < 2; ++j2) {
        const int colbase = ct * 256 + wc * 64 + (jh * 2 + j2) * 16 + (lane & 15);
        const float swv = sw[colbase];          // scalar load from L2
#pragma unroll
        for (int i = 0; i < 4; ++i)
#pragma unroll
          for (int q = 0; q < 4; ++q) {
            const int s = i * 4 + q;
            const float e = fmaf(-2.f, acc[i][j2][q], swv);
            const bool c1 = e < b1[s];
            b2[s] = c1 ? b1[s] : fminf(b2[s], e);
            bi[s] = c1 ? colbase : bi[s];
            b1[s] = fminf(b1[s], e);
          }
      }
    }
  }

  // merge across the 16 lanes sharing rows (lane&15 varies = different cols)
#pragma unroll
  for (int off = 1; off < 16; off <<= 1) {
#pragma unroll
    for (int s = 0; s < 16; ++s) {
      const float ob1 = __shfl_xor(b1[s], off);
      const float ob2 = __shfl_xor(b2[s], off);
      const int oi = __shfl_xor(bi[s], off);
      const float hi = fmaxf(b1[s], ob1);
      const bool take = ob1 < b1[s];
      b1[s] = fminf(b1[s], ob1);
      b2[s] = fminf(hi, fminf(b2[s], ob2));
      bi[s] = take ? oi : bi[s];
    }
  }
  __syncthreads();
  if ((lane & 15) == 0) {
#pragma unroll
    for (int i = 0; i < 4; ++i)
#pragma unroll
      for (int q = 0; q < 4; ++q) {
        const int s = i * 4 + q;
        const int r = wr * 64 + i * 16 + ((lane >> 4) & 3) * 4 + q;
        mrgB1[r][wc] = b1[s]; mrgB2[r][wc] = b2[s]; mrgI[r][wc] = bi[s];
      }
  }
  __syncthreads();
  if (t < TRM) {
    float bb = 3.4e38f, bs = 3.4e38f; int bidx = 0;
#pragma unroll
    for (int s2 = 0; s2 < 4; ++s2) {
      const float v1 = mrgB1[t][s2], v2 = mrgB2[t][s2];
      const int ii = mrgI[t][s2];
      if (v1 < bb) { bs = fminf(bb, v2); bb = v1; bidx = ii; }
      else bs = fminf(bs, v1);
    }
    const int grow = row0 + t;
    idxOut[grow] = bidx;
    idxOutF[grow] = (float)bidx;
    const bool flag = (bs - bb) < REPAIR_T;
    unsigned long long m = __ballot(flag);
    int base2 = 0;
    if ((t & 63) == 0) base2 = atomicAdd(flagCnt, __popcll(m));
    base2 = __shfl(base2, 0);
    if (flag) flagList[base2 + __popcll(m & ((1ull << (t & 63)) - 1ull))] = grow;
  }
}

// ========== exact repair of flagged rows (bit-exact fp32 emulation, 8 rows/block) ==========
#define RPB 8
__global__ __launch_bounds__(256) void vq_repair(const float* __restrict__ x,
                                                 const float* __restrict__ w,
                                                 const float* __restrict__ sw,
                                                 const int* __restrict__ flagCnt,
                                                 const int* __restrict__ flagList,
                                                 int* __restrict__ idxOut,
                                                 float* __restrict__ idxOutF) {
  __shared__ float xrow[RPB][DDIM];
  __shared__ float sxsh[RPB];
  __shared__ float rd[RPB][256];
  __shared__ int ri[RPB][256];
  const int t = threadIdx.x;
  const int cnt = flagCnt[0];
  for (int base = blockIdx.x * RPB; base < cnt; base += gridDim.x * RPB) {
    const int nr = min(RPB, cnt - base);
    int rowIdx[RPB];
#pragma unroll
    for (int r = 0; r < RPB; ++r)
      rowIdx[r] = flagList[base + ((r < nr) ? r : 0)];  // clamp padded slots (base < cnt)
    __syncthreads();
    for (int r = 0; r < nr; ++r)
      xrow[r][t] = x[(size_t)rowIdx[r] * DDIM + t];
    __syncthreads();
    // exact sx for this row: numpy pairwise order, no FMA
    if (t < nr) {
#pragma clang fp contract(off)
      float halves[2];
#pragma unroll
      for (int h = 0; h < 2; ++h) {
        const float* p = &xrow[t][h * 128];
        float acc[8];
#pragma unroll
        for (int j = 0; j < 8; ++j) { float v = p[j]; acc[j] = v * v; }
        for (int i = 8; i < 128; i += 8) {
#pragma unroll
          for (int j = 0; j < 8; ++j) { float v = p[i + j]; float e = v * v; acc[j] = acc[j] + e; }
        }
        halves[h] = ((acc[0] + acc[1]) + (acc[2] + acc[3])) + ((acc[4] + acc[5]) + (acc[6] + acc[7]));
      }
      sxsh[t] = halves[0] + halves[1];
    }
    __syncthreads();
    float bD[RPB]; int bI[RPB];
#pragma unroll
    for (int r = 0; r < RPB; ++r) { bD[r] = 3.4e38f; bI[r] = 0x7fffffff; }
    for (int g = 0; g < 4; ++g) {
      const int c = g * 256 + t;
      const float4* wrp = (const float4*)(w + (size_t)c * DDIM);
      float acc[RPB];
#pragma unroll
      for (int r = 0; r < RPB; ++r) acc[r] = 0.f;
      for (int d4 = 0; d4 < DDIM / 4; ++d4) {
        const float4 wv = wrp[d4];
#pragma unroll
        for (int e = 0; e < 4; ++e) {
          const float wvx = (e == 0) ? wv.x : (e == 1) ? wv.y : (e == 2) ? wv.z : wv.w;
#pragma unroll
          for (int r = 0; r < RPB; ++r) acc[r] = fmaf(xrow[r][d4 * 4 + e], wvx, acc[r]);
        }
      }
      const float swc = sw[c];
#pragma unroll
      for (int r = 0; r < RPB; ++r) {
        // dist = fl(fl(sx+sw) - 2*dot); g ascending => lowest code wins ties
        const float tt = sxsh[r] + swc;
        const float dist = tt - 2.0f * acc[r];
        if (dist < bD[r]) { bD[r] = dist; bI[r] = c; }
      }
    }
#pragma unroll
    for (int r = 0; r < RPB; ++r) { rd[r][t] = bD[r]; ri[r][t] = bI[r]; }
    __syncthreads();
    for (int s2 = 128; s2 > 0; s2 >>= 1) {
      if (t < s2) {
#pragma unroll
        for (int r = 0; r < RPB; ++r) {
          const float od = rd[r][t + s2]; const int oi = ri[r][t + s2];
          if (od < rd[r][t] || (od == rd[r][t] && oi < ri[r][t])) { rd[r][t] = od; ri[r][t] = oi; }
        }
      }
      __syncthreads();
    }
    if (t < nr) {
      const int row = rowIdx[t];
      idxOut[row] = ri[t][0];
      idxOutF[row] = (float)ri[t][0];
    }
    __syncthreads();
  }
}

// ====== gather + straight-through out + qloss partial + histogram ======
__global__ __launch_bounds__(256) void vq_quantize(const float* __restrict__ x,
                                                   const float* __restrict__ w,
                                                   const int* __restrict__ idxArr,
                                                   float* __restrict__ qout,
                                                   int* __restrict__ counts,
                                                   float* __restrict__ partialQ) {
  const int wave = threadIdx.x >> 6;
  const int lane = threadIdx.x & 63;
  const int base = blockIdx.x * 64 + wave * 16;
  float s = 0.f;
#pragma unroll 4
  for (int r = 0; r < 16; ++r) {
    const int row = base + r;
    const int idx = idxArr[row];
    float4 xv = ((const float4*)(x + (size_t)row * DDIM))[lane];
    float4 qv = ((const float4*)(w + (size_t)idx * DDIM))[lane];
    float dx = qv.x - xv.x, dy = qv.y - xv.y, dz = qv.z - xv.z, dw = qv.w - xv.w;
    float4 o;
    o.x = xv.x + dx; o.y = xv.y + dy; o.z = xv.z + dz; o.w = xv.w + dw;
    ((float4*)(qout + (size_t)row * DDIM))[lane] = o;
    s += dx * dx + dy * dy + dz * dz + dw * dw;
    if (lane == 0) atomicAdd(&counts[idx], 1);
  }
  double d = s;
  for (int off = 32; off > 0; off >>= 1) d += __shfl_down(d, off);
  __shared__ double red[4];
  if (lane == 0) red[wave] = d;
  __syncthreads();
  if (threadIdx.x == 0)
    partialQ[blockIdx.x] = (float)(red[0] + red[1] + red[2] + red[3]);
}

// ================= compactness =================
__global__ __launch_bounds__(256) void vq_compact(const float* __restrict__ w,
                                                  const float* __restrict__ sw,
                                                  float* __restrict__ partialP) {
  const int i = blockIdx.x;
  const int t = threadIdx.x;
  __shared__ float wi[DDIM];
  wi[t] = w[(size_t)i * DDIM + t];
  __syncthreads();
  float swi = sw[i];
  double s = 0.0;
  for (int j = i + 1 + t; j < KCODES; j += 256) {
    const float4* wj = (const float4*)(w + (size_t)j * DDIM);
    const float4* wi4 = (const float4*)wi;
    float acc = 0.f;
#pragma unroll 8
    for (int d4 = 0; d4 < DDIM / 4; ++d4) {
      float4 a = wi4[d4];
      float4 b = wj[d4];
      acc += a.x * b.x + a.y * b.y + a.z * b.z + a.w * b.w;
    }
    float pd2 = (swi + sw[j]) - 2.0f * acc;
    s += (double)sqrtf(fmaxf(pd2, 1e-12f));
  }
  for (int off = 32; off > 0; off >>= 1) s += __shfl_down(s, off);
  __shared__ double red[4];
  if ((t & 63) == 0) red[t >> 6] = s;
  __syncthreads();
  if (t == 0)
    partialP[i] = (float)(red[0] + red[1] + red[2] + red[3]);
}

// ========== finalize ==========
__global__ __launch_bounds__(1024) void vq_final(const float* __restrict__ partialQ,
                                                 const float* __restrict__ partialP,
                                                 const int* __restrict__ counts,
                                                 float* __restrict__ out) {
  const int t = threadIdx.x;
  const int lane = t & 63, wave = t >> 6;
  double q = (double)partialQ[t];
  double p = (double)partialP[t];
  double u = (double)fabsf((float)counts[t] - 64.0f);
  for (int off = 32; off > 0; off >>= 1) {
    q += __shfl_down(q, off);
    p += __shfl_down(p, off);
    u += __shfl_down(u, off);
  }
  __shared__ double redQ[16], redP[16], redU[16];
  if (lane == 0) { redQ[wave] = q; redP[wave] = p; redU[wave] = u; }
  __syncthreads();
  if (t == 0) {
    double sq = 0, sp = 0, su = 0;
    for (int j = 0; j < 16; ++j) { sq += redQ[j]; sp += redP[j]; su += redU[j]; }
    float m = (float)(sq / 16777216.0);
    out[ND_TOT] = m + 0.25f * m;
    out[ND_TOT + 1] = (float)(su / 1024.0);
    out[ND_TOT + 2] = (float)(2.0 * sp / 523776.0);
  }
}

extern "C" void kernel_launch(void* const* d_in, const int* in_sizes, int n_in,
                              void* d_out, int out_size, void* d_ws, size_t ws_size,
                              hipStream_t stream) {
  const float* x = (const float*)d_in[0];
  const float* w = (const float*)d_in[1];
  float* out = (float*)d_out;

  char* ws = (char*)d_ws;
  int* wsIdx    = (int*)(ws + WS_IDX);
  int* counts   = (int*)(ws + WS_COUNTS);
  float* swv    = (float*)(ws + WS_SW);
  float* partQ  = (float*)(ws + WS_PARTQ);
  float* partP  = (float*)(ws + WS_PARTP);
  int* flagCnt  = (int*)(ws + WS_FLAGCNT);
  int* flagList = (int*)(ws + WS_FLAGLIST);
  unsigned short* whS = (unsigned short*)(ws + WS_WH);
  unsigned short* wlS = (unsigned short*)(ws + WS_WL);

  // bf16 splits of x live in the quantized-output region (overwritten by vq_quantize later)
  unsigned short* xhS = (unsigned short*)d_out;
  unsigned short* xlS = xhS + (size_t)ND_TOT;

  hipMemsetAsync(ws + WS_COUNTS, 0, 4096, stream);
  hipMemsetAsync(ws + WS_FLAGCNT, 0, 4, stream);

  vq_split_x<<<2048, 256, 0, stream>>>(x, xhS, xlS);
  vq_prep_w<<<8, 128, 0, stream>>>(w, swv, whS, wlS);
  vq_argmin_mfma<<<NROWS / TRM, 512, 0, stream>>>(xhS, xlS, whS, wlS, swv,
                                                  wsIdx, out + ND_TOT + 3, flagCnt, flagList);
  vq_repair<<<1024, 256, 0, stream>>>(x, w, swv, flagCnt, flagList, wsIdx, out + ND_TOT + 3);
  vq_quantize<<<1024, 256, 0, stream>>>(x, w, wsIdx, out, counts, partQ);
  vq_compact<<<KCODES, 256, 0, stream>>>(w, swv, partP);
  vq_final<<<1, 1024, 0, stream>>>(partQ, partP, counts, out);
}

// Round 9
// 422.381 us; speedup vs baseline: 1.6477x; 1.6477x over previous
//
#include <hip/hip_runtime.h>
#include <math.h>

#define NROWS 65536
#define KCODES 1024
#define DDIM 256
#define ND_TOT (NROWS * DDIM)

// ---------- ws layout (bytes) ----------
#define WS_IDX      0         // int idx[N]          256KB
#define WS_COUNTS   262144    // int counts[K]       4KB
#define WS_SW       266240    // float sw[K]         4KB
#define WS_PARTQ    532480    // float partQ[1024]   4KB
#define WS_PARTP    536576    // float partP[1024]   4KB
#define WS_FLAGCNT  540672    // int                 (256B slot)
#define WS_FLAGLIST 540928    // int flagList[N]     256KB
#define WS_WH       803072    // ushort wh[K*256]    512KB
#define WS_WL       1327360   // ushort wl[K*256]    512KB

typedef float f32x4 __attribute__((ext_vector_type(4)));
typedef short bf16x8 __attribute__((ext_vector_type(8)));

__device__ inline unsigned short f2bf(float f) {
  unsigned u = __float_as_uint(f);
  u += 0x7FFFu + ((u >> 16) & 1u);   // RNE to bf16
  return (unsigned short)(u >> 16);
}
__device__ inline float bf2f(unsigned short h) {
  return __uint_as_float(((unsigned)h) << 16);
}

__device__ inline void gload16(const void* g, void* l) {
  __builtin_amdgcn_global_load_lds((const __attribute__((address_space(1))) void*)g,
                                   (__attribute__((address_space(3))) void*)l, 16, 0, 0);
}

// ========== elementwise bf16 split of x (fully coalesced, grid-stride) ==========
__global__ __launch_bounds__(256) void vq_split_x(const float* __restrict__ x,
                                                  unsigned short* __restrict__ xh,
                                                  unsigned short* __restrict__ xl) {
  const size_t stride = (size_t)gridDim.x * 256;
  for (size_t i = (size_t)blockIdx.x * 256 + threadIdx.x; i < ND_TOT / 8; i += stride) {
    const size_t e = i * 8;
    float4 a = *(const float4*)&x[e];
    float4 b = *(const float4*)&x[e + 4];
    float fv[8] = {a.x, a.y, a.z, a.w, b.x, b.y, b.z, b.w};
    union { unsigned short us[8]; uint4 v; } ph, pl;
#pragma unroll
    for (int k = 0; k < 8; ++k) {
      unsigned short h = f2bf(fv[k]);
      ph.us[k] = h;
      pl.us[k] = f2bf(fv[k] - bf2f(h));   // exact in fp32
    }
    *(uint4*)&xh[e] = ph.v;
    *(uint4*)&xl[e] = pl.v;
  }
}

// ========== w prep: bf16 split + exact sw (numpy-pairwise, tiny) ==========
__global__ __launch_bounds__(128) void vq_prep_w(const float* __restrict__ w,
                                                 float* __restrict__ sw,
                                                 unsigned short* __restrict__ wh,
                                                 unsigned short* __restrict__ wl) {
#pragma clang fp contract(off)
  int k = blockIdx.x * 128 + threadIdx.x;
  if (k >= KCODES) return;
  const float* src = w + (size_t)k * DDIM;
  unsigned short* hdst = wh + (size_t)k * DDIM;
  unsigned short* ldst = wl + (size_t)k * DDIM;
  for (int i = 0; i < DDIM; i += 8) {
    float4 a = *(const float4*)&src[i];
    float4 b = *(const float4*)&src[i + 4];
    float fv[8] = {a.x, a.y, a.z, a.w, b.x, b.y, b.z, b.w};
    union { unsigned short us[8]; uint4 v; } ph, pl;
#pragma unroll
    for (int e = 0; e < 8; ++e) {
      unsigned short h = f2bf(fv[e]);
      ph.us[e] = h;
      pl.us[e] = f2bf(fv[e] - bf2f(h));
    }
    *(uint4*)&hdst[i] = ph.v;
    *(uint4*)&ldst[i] = pl.v;
  }
  float halves[2];
#pragma unroll
  for (int h = 0; h < 2; ++h) {
    const float* p = src + h * 128;
    float acc[8];
#pragma unroll
    for (int j = 0; j < 8; ++j) { float v = p[j]; acc[j] = v * v; }
    for (int i = 8; i < 128; i += 8) {
#pragma unroll
      for (int j = 0; j < 8; ++j) { float v = p[i + j]; float e = v * v; acc[j] = acc[j] + e; }
    }
    halves[h] = ((acc[0] + acc[1]) + (acc[2] + acc[3])) + ((acc[4] + acc[5]) + (acc[6] + acc[7]));
  }
  sw[k] = halves[0] + halves[1];
}

// ========== MFMA split-bf16 distance + top2 argmin ==========
// x-stationary barrier-free design, 4-wave blocks:
//   - 256 threads = 4 waves = exactly 1 wave/SIMD -> launch_bounds(256,1) -> VGPR cap 512
//     (R7/R8 lesson: 8-wave blocks cap VGPR at 128 -> massive scratch spill)
//   - x (128 rows, full D, h+l splits) in 128KB LDS, staged once, XOR-swizzled
//   - w fragments read per-lane direct from global; 1MB splits stay L2-resident
//   - zero barriers in the ct loop
#define TRM 128
// Flag threshold: hard bound for a reference-order flip is
//   approx-e error (<=~6e-6) + reference rounding reorder width (~6.1e-5).
// Total ~7.3e-5; T=1.5e-4 keeps 2x margin.
#define REPAIR_T 1.5e-4f

__global__ __launch_bounds__(256, 1) void vq_argmin_mfma(
    const unsigned short* __restrict__ xh, const unsigned short* __restrict__ xl,
    const unsigned short* __restrict__ wh, const unsigned short* __restrict__ wl,
    const float* __restrict__ sw,
    int* __restrict__ idxOut, float* __restrict__ idxOutF,
    int* __restrict__ flagCnt, int* __restrict__ flagList) {
  __shared__ __align__(16) unsigned short lds_xh[TRM * DDIM];  // 64KB, full-D, swizzled
  __shared__ __align__(16) unsigned short lds_xl[TRM * DDIM];  // 64KB
  __shared__ float mrgB1[TRM][2];
  __shared__ float mrgB2[TRM][2];
  __shared__ int   mrgI[TRM][2];

  const int t = threadIdx.x;                // 256 threads = 4 waves
  const int lane = t & 63, wv = t >> 6;
  const int wr = wv >> 1, wc = wv & 1;      // wave grid 2x2: rows 64*wr, cols 64*wc per tile
  const int row0 = blockIdx.x * TRM;

  const char* xhB = (const char*)xh;
  const char* xlB = (const char*)xl;
  const char* whB = (const char*)wh;
  const char* wlB = (const char*)wl;

  // ---- one-time x staging: per wave 32 rows x 512B per array; 2 rows per gload16 instr ----
#pragma unroll
  for (int it = 0; it < 16; ++it) {
    const int rowl = wv * 32 + it * 2 + (lane >> 5);
    const int binrow = ((lane & 31) * 16) ^ ((rowl & 7) << 4);  // pre-swizzled source
    const size_t go = (size_t)(row0 + rowl) * 512 + (size_t)binrow;
    gload16(xhB + go, (char*)lds_xh + (wv * 32 + it * 2) * 512);
    gload16(xlB + go, (char*)lds_xl + (wv * 32 + it * 2) * 512);
  }
  __syncthreads();   // drains vmcnt; x LDS is read-only from here on

  float b1[16], b2[16];
  int bi[16];
#pragma unroll
  for (int s = 0; s < 16; ++s) { b1[s] = 3.4e38f; b2[s] = 3.4e38f; bi[s] = 0; }

  for (int ct = 0; ct < 8; ++ct) {          // 128 codes per iter; wave covers its 64-col half
    f32x4 acc[4][4];
#pragma unroll
    for (int i = 0; i < 4; ++i)
#pragma unroll
      for (int j = 0; j < 4; ++j) acc[i][j] = (f32x4){0.f, 0.f, 0.f, 0.f};

#pragma unroll
    for (int dt = 0; dt < 4; ++dt) {
#pragma unroll
      for (int kh = 0; kh < 2; ++kh) {
        const int kb = dt * 128 + kh * 64 + ((lane >> 4) & 3) * 16;
        bf16x8 ah[4], al[4];
#pragma unroll
        for (int i = 0; i < 4; ++i) {
          const int r = wr * 64 + i * 16 + (lane & 15);
          const int off = r * 512 + (kb ^ ((r & 7) << 4));
          ah[i] = *(const bf16x8*)((const char*)lds_xh + off);
          al[i] = *(const bf16x8*)((const char*)lds_xl + off);
        }
#pragma unroll
        for (int j = 0; j < 4; ++j) {
          const int c = ct * 128 + wc * 64 + j * 16 + (lane & 15);
          const size_t wo = (size_t)c * 512 + (size_t)kb;    // no swizzle: direct global
          bf16x8 bh = *(const bf16x8*)(whB + wo);
          bf16x8 bl = *(const bf16x8*)(wlB + wo);
#pragma unroll
          for (int i = 0; i < 4; ++i) {
            acc[i][j] = __builtin_amdgcn_mfma_f32_16x16x32_bf16(ah[i], bh, acc[i][j], 0, 0, 0);
            acc[i][j] = __builtin_amdgcn_mfma_f32_16x16x32_bf16(ah[i], bl, acc[i][j], 0, 0, 0);
            acc[i][j] = __builtin_amdgcn_mfma_f32_16x16x32_bf16(al[i], bh, acc[i][j], 0, 0, 0);
          }
        }
      }
    }

    // top-2 update in e-space: e = sw - 2*dot (sx drops out of per-row argmin)
#pragma unroll
    for (int j = 0; j < 4; ++j) {
      const int colbase = ct * 128 + wc * 64 + j * 16 + (lane & 15);
      const float swv = sw[colbase];          // scalar load from L2
#pragma unroll
      for (int i = 0; i < 4; ++i)
#pragma unroll
        for (int q = 0; q < 4; ++q) {
          const int s = i * 4 + q;
          const float e = fmaf(-2.f, acc[i][j][q], swv);
          const bool c1 = e < b1[s];
          b2[s] = c1 ? b1[s] : fminf(b2[s], e);
          bi[s] = c1 ? colbase : bi[s];
          b1[s] = fminf(b1[s], e);
        }
    }
  }

  // merge across the 16 lanes sharing rows (lane&15 varies = different cols)
#pragma unroll
  for (int off = 1; off < 16; off <<= 1) {
#pragma unroll
    for (int s = 0; s < 16; ++s) {
      const float ob1 = __shfl_xor(b1[s], off);
      const float ob2 = __shfl_xor(b2[s], off);
      const int oi = __shfl_xor(bi[s], off);
      const float hi = fmaxf(b1[s], ob1);
      const bool take = ob1 < b1[s];
      b1[s] = fminf(b1[s], ob1);
      b2[s] = fminf(hi, fminf(b2[s], ob2));
      bi[s] = take ? oi : bi[s];
    }
  }
  __syncthreads();
  if ((lane & 15) == 0) {
#pragma unroll
    for (int i = 0; i < 4; ++i)
#pragma unroll
      for (int q = 0; q < 4; ++q) {
        const int s = i * 4 + q;
        const int r = wr * 64 + i * 16 + ((lane >> 4) & 3) * 4 + q;
        mrgB1[r][wc] = b1[s]; mrgB2[r][wc] = b2[s]; mrgI[r][wc] = bi[s];
      }
  }
  __syncthreads();
  if (t < TRM) {
    float bb = 3.4e38f, bs = 3.4e38f; int bidx = 0;
#pragma unroll
    for (int s2 = 0; s2 < 2; ++s2) {
      const float v1 = mrgB1[t][s2], v2 = mrgB2[t][s2];
      const int ii = mrgI[t][s2];
      if (v1 < bb) { bs = fminf(bb, v2); bb = v1; bidx = ii; }
      else bs = fminf(bs, v1);
    }
    const int grow = row0 + t;
    idxOut[grow] = bidx;
    idxOutF[grow] = (float)bidx;
    const bool flag = (bs - bb) < REPAIR_T;
    unsigned long long m = __ballot(flag);
    int base2 = 0;
    if ((t & 63) == 0) base2 = atomicAdd(flagCnt, __popcll(m));
    base2 = __shfl(base2, 0);
    if (flag) flagList[base2 + __popcll(m & ((1ull << (t & 63)) - 1ull))] = grow;
  }
}

// ========== exact repair of flagged rows (bit-exact fp32 emulation, 8 rows/block) ==========
#define RPB 8
__global__ __launch_bounds__(256) void vq_repair(const float* __restrict__ x,
                                                 const float* __restrict__ w,
                                                 const float* __restrict__ sw,
                                                 const int* __restrict__ flagCnt,
                                                 const int* __restrict__ flagList,
                                                 int* __restrict__ idxOut,
                                                 float* __restrict__ idxOutF) {
  __shared__ float xrow[RPB][DDIM];
  __shared__ float sxsh[RPB];
  __shared__ float rd[RPB][256];
  __shared__ int ri[RPB][256];
  const int t = threadIdx.x;
  const int cnt = flagCnt[0];
  for (int base = blockIdx.x * RPB; base < cnt; base += gridDim.x * RPB) {
    const int nr = min(RPB, cnt - base);
    int rowIdx[RPB];
#pragma unroll
    for (int r = 0; r < RPB; ++r)
      rowIdx[r] = flagList[base + ((r < nr) ? r : 0)];  // clamp padded slots (base < cnt)
    __syncthreads();
    for (int r = 0; r < nr; ++r)
      xrow[r][t] = x[(size_t)rowIdx[r] * DDIM + t];
    __syncthreads();
    // exact sx for this row: numpy pairwise order, no FMA
    if (t < nr) {
#pragma clang fp contract(off)
      float halves[2];
#pragma unroll
      for (int h = 0; h < 2; ++h) {
        const float* p = &xrow[t][h * 128];
        float acc[8];
#pragma unroll
        for (int j = 0; j < 8; ++j) { float v = p[j]; acc[j] = v * v; }
        for (int i = 8; i < 128; i += 8) {
#pragma unroll
          for (int j = 0; j < 8; ++j) { float v = p[i + j]; float e = v * v; acc[j] = acc[j] + e; }
        }
        halves[h] = ((acc[0] + acc[1]) + (acc[2] + acc[3])) + ((acc[4] + acc[5]) + (acc[6] + acc[7]));
      }
      sxsh[t] = halves[0] + halves[1];
    }
    __syncthreads();
    float bD[RPB]; int bI[RPB];
#pragma unroll
    for (int r = 0; r < RPB; ++r) { bD[r] = 3.4e38f; bI[r] = 0x7fffffff; }
    for (int g = 0; g < 4; ++g) {
      const int c = g * 256 + t;
      const float4* wrp = (const float4*)(w + (size_t)c * DDIM);
      float acc[RPB];
#pragma unroll
      for (int r = 0; r < RPB; ++r) acc[r] = 0.f;
      for (int d4 = 0; d4 < DDIM / 4; ++d4) {
        const float4 wv = wrp[d4];
#pragma unroll
        for (int e = 0; e < 4; ++e) {
          const float wvx = (e == 0) ? wv.x : (e == 1) ? wv.y : (e == 2) ? wv.z : wv.w;
#pragma unroll
          for (int r = 0; r < RPB; ++r) acc[r] = fmaf(xrow[r][d4 * 4 + e], wvx, acc[r]);
        }
      }
      const float swc = sw[c];
#pragma unroll
      for (int r = 0; r < RPB; ++r) {
        // dist = fl(fl(sx+sw) - 2*dot); g ascending => lowest code wins ties
        const float tt = sxsh[r] + swc;
        const float dist = tt - 2.0f * acc[r];
        if (dist < bD[r]) { bD[r] = dist; bI[r] = c; }
      }
    }
#pragma unroll
    for (int r = 0; r < RPB; ++r) { rd[r][t] = bD[r]; ri[r][t] = bI[r]; }
    __syncthreads();
    for (int s2 = 128; s2 > 0; s2 >>= 1) {
      if (t < s2) {
#pragma unroll
        for (int r = 0; r < RPB; ++r) {
          const float od = rd[r][t + s2]; const int oi = ri[r][t + s2];
          if (od < rd[r][t] || (od == rd[r][t] && oi < ri[r][t])) { rd[r][t] = od; ri[r][t] = oi; }
        }
      }
      __syncthreads();
    }
    if (t < nr) {
      const int row = rowIdx[t];
      idxOut[row] = ri[t][0];
      idxOutF[row] = (float)ri[t][0];
    }
    __syncthreads();
  }
}

// ====== gather + straight-through out + qloss partial + histogram ======
__global__ __launch_bounds__(256) void vq_quantize(const float* __restrict__ x,
                                                   const float* __restrict__ w,
                                                   const int* __restrict__ idxArr,
                                                   float* __restrict__ qout,
                                                   int* __restrict__ counts,
                                                   float* __restrict__ partialQ) {
  const int wave = threadIdx.x >> 6;
  const int lane = threadIdx.x & 63;
  const int base = blockIdx.x * 64 + wave * 16;
  float s = 0.f;
#pragma unroll 4
  for (int r = 0; r < 16; ++r) {
    const int row = base + r;
    const int idx = idxArr[row];
    float4 xv = ((const float4*)(x + (size_t)row * DDIM))[lane];
    float4 qv = ((const float4*)(w + (size_t)idx * DDIM))[lane];
    float dx = qv.x - xv.x, dy = qv.y - xv.y, dz = qv.z - xv.z, dw = qv.w - xv.w;
    float4 o;
    o.x = xv.x + dx; o.y = xv.y + dy; o.z = xv.z + dz; o.w = xv.w + dw;
    ((float4*)(qout + (size_t)row * DDIM))[lane] = o;
    s += dx * dx + dy * dy + dz * dz + dw * dw;
    if (lane == 0) atomicAdd(&counts[idx], 1);
  }
  double d = s;
  for (int off = 32; off > 0; off >>= 1) d += __shfl_down(d, off);
  __shared__ double red[4];
  if (lane == 0) red[wave] = d;
  __syncthreads();
  if (threadIdx.x == 0)
    partialQ[blockIdx.x] = (float)(red[0] + red[1] + red[2] + red[3]);
}

// ================= compactness =================
__global__ __launch_bounds__(256) void vq_compact(const float* __restrict__ w,
                                                  const float* __restrict__ sw,
                                                  float* __restrict__ partialP) {
  const int i = blockIdx.x;
  const int t = threadIdx.x;
  __shared__ float wi[DDIM];
  wi[t] = w[(size_t)i * DDIM + t];
  __syncthreads();
  float swi = sw[i];
  double s = 0.0;
  for (int j = i + 1 + t; j < KCODES; j += 256) {
    const float4* wj = (const float4*)(w + (size_t)j * DDIM);
    const float4* wi4 = (const float4*)wi;
    float acc = 0.f;
#pragma unroll 8
    for (int d4 = 0; d4 < DDIM / 4; ++d4) {
      float4 a = wi4[d4];
      float4 b = wj[d4];
      acc += a.x * b.x + a.y * b.y + a.z * b.z + a.w * b.w;
    }
    float pd2 = (swi + sw[j]) - 2.0f * acc;
    s += (double)sqrtf(fmaxf(pd2, 1e-12f));
  }
  for (int off = 32; off > 0; off >>= 1) s += __shfl_down(s, off);
  __shared__ double red[4];
  if ((t & 63) == 0) red[t >> 6] = s;
  __syncthreads();
  if (t == 0)
    partialP[i] = (float)(red[0] + red[1] + red[2] + red[3]);
}

// ========== finalize ==========
__global__ __launch_bounds__(1024) void vq_final(const float* __restrict__ partialQ,
                                                 const float* __restrict__ partialP,
                                                 const int* __restrict__ counts,
                                                 float* __restrict__ out) {
  const int t = threadIdx.x;
  const int lane = t & 63, wave = t >> 6;
  double q = (double)partialQ[t];
  double p = (double)partialP[t];
  double u = (double)fabsf((float)counts[t] - 64.0f);
  for (int off = 32; off > 0; off >>= 1) {
    q += __shfl_down(q, off);
    p += __shfl_down(p, off);
    u += __shfl_down(u, off);
  }
  __shared__ double redQ[16], redP[16], redU[16];
  if (lane == 0) { redQ[wave] = q; redP[wave] = p; redU[wave] = u; }
  __syncthreads();
  if (t == 0) {
    double sq = 0, sp = 0, su = 0;
    for (int j = 0; j < 16; ++j) { sq += redQ[j]; sp += redP[j]; su += redU[j]; }
    float m = (float)(sq / 16777216.0);
    out[ND_TOT] = m + 0.25f * m;
    out[ND_TOT + 1] = (float)(su / 1024.0);
    out[ND_TOT + 2] = (float)(2.0 * sp / 523776.0);
  }
}

extern "C" void kernel_launch(void* const* d_in, const int* in_sizes, int n_in,
                              void* d_out, int out_size, void* d_ws, size_t ws_size,
                              hipStream_t stream) {
  const float* x = (const float*)d_in[0];
  const float* w = (const float*)d_in[1];
  float* out = (float*)d_out;

  char* ws = (char*)d_ws;
  int* wsIdx    = (int*)(ws + WS_IDX);
  int* counts   = (int*)(ws + WS_COUNTS);
  float* swv    = (float*)(ws + WS_SW);
  float* partQ  = (float*)(ws + WS_PARTQ);
  float* partP  = (float*)(ws + WS_PARTP);
  int* flagCnt  = (int*)(ws + WS_FLAGCNT);
  int* flagList = (int*)(ws + WS_FLAGLIST);
  unsigned short* whS = (unsigned short*)(ws + WS_WH);
  unsigned short* wlS = (unsigned short*)(ws + WS_WL);

  // bf16 splits of x live in the quantized-output region (overwritten by vq_quantize later)
  unsigned short* xhS = (unsigned short*)d_out;
  unsigned short* xlS = xhS + (size_t)ND_TOT;

  hipMemsetAsync(ws + WS_COUNTS, 0, 4096, stream);
  hipMemsetAsync(ws + WS_FLAGCNT, 0, 4, stream);

  vq_split_x<<<2048, 256, 0, stream>>>(x, xhS, xlS);
  vq_prep_w<<<8, 128, 0, stream>>>(w, swv, whS, wlS);
  vq_argmin_mfma<<<NROWS / TRM, 256, 0, stream>>>(xhS, xlS, whS, wlS, swv,
                                                  wsIdx, out + ND_TOT + 3, flagCnt, flagList);
  vq_repair<<<1024, 256, 0, stream>>>(x, w, swv, flagCnt, flagList, wsIdx, out + ND_TOT + 3);
  vq_quantize<<<1024, 256, 0, stream>>>(x, w, wsIdx, out, counts, partQ);
  vq_compact<<<KCODES, 256, 0, stream>>>(w, swv, partP);
  vq_final<<<1, 1024, 0, stream>>>(partQ, partP, counts, out);
}

// Round 10
// 344.860 us; speedup vs baseline: 2.0181x; 1.2248x over previous
//
#include <hip/hip_runtime.h>
#include <math.h>

#define NROWS 65536
#define KCODES 1024
#define DDIM 256
#define ND_TOT (NROWS * DDIM)

// ---------- ws layout (bytes) ----------
#define WS_IDX      0         // int idx[N]          256KB
#define WS_COUNTS   262144    // int counts[K]       4KB
#define WS_SW       266240    // float sw[K]         4KB
#define WS_PARTQ    532480    // float partQ[1024]   4KB
#define WS_PARTP    536576    // float partP[1024]   4KB
#define WS_FLAGCNT  540672    // int                 (256B slot)
#define WS_FLAGLIST 540928    // int flagList[N]     256KB
#define WS_WH       803072    // ushort wh[K*256]    512KB
#define WS_WL       1327360   // ushort wl[K*256]    512KB

typedef float f32x4 __attribute__((ext_vector_type(4)));
typedef short bf16x8 __attribute__((ext_vector_type(8)));

__device__ inline unsigned short f2bf(float f) {
  unsigned u = __float_as_uint(f);
  u += 0x7FFFu + ((u >> 16) & 1u);   // RNE to bf16
  return (unsigned short)(u >> 16);
}
__device__ inline float bf2f(unsigned short h) {
  return __uint_as_float(((unsigned)h) << 16);
}

__device__ inline void gload16(const void* g, void* l) {
  __builtin_amdgcn_global_load_lds((const __attribute__((address_space(1))) void*)g,
                                   (__attribute__((address_space(3))) void*)l, 16, 0, 0);
}

// ========== fused: x bf16-split (grid-stride) + w prep + counter zeroing ==========
// blocks [0,2048): split x; block 0 additionally zeroes counts+flagCnt
// blocks [2048,2052): w split + exact sw (numpy-pairwise)
__global__ __launch_bounds__(256) void vq_prep(const float* __restrict__ x,
                                               const float* __restrict__ w,
                                               unsigned short* __restrict__ xh,
                                               unsigned short* __restrict__ xl,
                                               float* __restrict__ sw,
                                               unsigned short* __restrict__ wh,
                                               unsigned short* __restrict__ wl,
                                               int* __restrict__ counts,
                                               int* __restrict__ flagCnt) {
  const int b = blockIdx.x;
  const int t = threadIdx.x;
  if (b >= 2048) {
#pragma clang fp contract(off)
    const int k = (b - 2048) * 256 + t;
    if (k >= KCODES) return;
    const float* src = w + (size_t)k * DDIM;
    unsigned short* hdst = wh + (size_t)k * DDIM;
    unsigned short* ldst = wl + (size_t)k * DDIM;
    for (int i = 0; i < DDIM; i += 8) {
      float4 a = *(const float4*)&src[i];
      float4 bb = *(const float4*)&src[i + 4];
      float fv[8] = {a.x, a.y, a.z, a.w, bb.x, bb.y, bb.z, bb.w};
      union { unsigned short us[8]; uint4 v; } ph, pl;
#pragma unroll
      for (int e = 0; e < 8; ++e) {
        unsigned short h = f2bf(fv[e]);
        ph.us[e] = h;
        pl.us[e] = f2bf(fv[e] - bf2f(h));
      }
      *(uint4*)&hdst[i] = ph.v;
      *(uint4*)&ldst[i] = pl.v;
    }
    float halves[2];
#pragma unroll
    for (int h = 0; h < 2; ++h) {
      const float* p = src + h * 128;
      float acc[8];
#pragma unroll
      for (int j = 0; j < 8; ++j) { float v = p[j]; acc[j] = v * v; }
      for (int i = 8; i < 128; i += 8) {
#pragma unroll
        for (int j = 0; j < 8; ++j) { float v = p[i + j]; float e = v * v; acc[j] = acc[j] + e; }
      }
      halves[h] = ((acc[0] + acc[1]) + (acc[2] + acc[3])) + ((acc[4] + acc[5]) + (acc[6] + acc[7]));
    }
    sw[k] = halves[0] + halves[1];
    return;
  }
  if (b == 0) {
#pragma unroll
    for (int j = 0; j < 4; ++j) counts[j * 256 + t] = 0;
    if (t == 0) flagCnt[0] = 0;
  }
  const size_t stride = (size_t)2048 * 256;
  for (size_t i = (size_t)b * 256 + t; i < ND_TOT / 8; i += stride) {
    const size_t e = i * 8;
    float4 a = *(const float4*)&x[e];
    float4 bb = *(const float4*)&x[e + 4];
    float fv[8] = {a.x, a.y, a.z, a.w, bb.x, bb.y, bb.z, bb.w};
    union { unsigned short us[8]; uint4 v; } ph, pl;
#pragma unroll
    for (int k = 0; k < 8; ++k) {
      unsigned short h = f2bf(fv[k]);
      ph.us[k] = h;
      pl.us[k] = f2bf(fv[k] - bf2f(h));   // exact in fp32
    }
    *(uint4*)&xh[e] = ph.v;
    *(uint4*)&xl[e] = pl.v;
  }
}

// ========== MFMA split-bf16 distance + top2 argmin (R6 structure, proven 111us) ==========
#define TRM 128
#define BKM 64
// Flag threshold: hard bound for a reference-order flip is
//   approx-e error (<=~6e-6) + reference rounding reorder width (~6.1e-5).
// Total ~7.3e-5; T=1.5e-4 keeps 2x margin.
#define REPAIR_T 1.5e-4f

__global__ __launch_bounds__(256, 2) void vq_argmin_mfma(
    const unsigned short* __restrict__ xh, const unsigned short* __restrict__ xl,
    const unsigned short* __restrict__ wh, const unsigned short* __restrict__ wl,
    const float* __restrict__ sw,
    int* __restrict__ idxOut, float* __restrict__ idxOutF,
    int* __restrict__ flagCnt, int* __restrict__ flagList) {
  __shared__ __align__(16) unsigned short lds_xh[TRM * BKM];  // 16KB each, XOR-swizzled
  __shared__ __align__(16) unsigned short lds_xl[TRM * BKM];
  __shared__ __align__(16) unsigned short lds_wh[TRM * BKM];
  __shared__ __align__(16) unsigned short lds_wl[TRM * BKM];
  __shared__ __align__(16) float sws[KCODES];
  __shared__ float mrgB1[TRM][2];
  __shared__ float mrgB2[TRM][2];
  __shared__ int   mrgI[TRM][2];

  const int t = threadIdx.x;
  const int lane = t & 63, wv = t >> 6;
  const int wr = wv >> 1, wc = wv & 1;     // wave quadrant: rows 64*wr, cols 64*wc
  const int row0 = blockIdx.x * TRM;

  { f32x4 v = ((const f32x4*)sw)[t]; ((f32x4*)sws)[t] = v; }  // 1024 floats

  const int laneRow = lane >> 3;                                  // 0..7
  const int srcswz = ((lane & 7) * 16) ^ ((laneRow & 7) << 4);    // pre-swizzled source chunk
  const char* xhB = (const char*)xh;
  const char* xlB = (const char*)xl;
  const char* whB = (const char*)wh;
  const char* wlB = (const char*)wl;

  float b1[16], b2[16];
  int bi[16];
#pragma unroll
  for (int s = 0; s < 16; ++s) { b1[s] = 3.4e38f; b2[s] = 3.4e38f; bi[s] = 0; }

  for (int ct = 0; ct < KCODES / TRM; ++ct) {
    f32x4 acc[4][4];
#pragma unroll
    for (int i = 0; i < 4; ++i)
#pragma unroll
      for (int j = 0; j < 4; ++j) acc[i][j] = (f32x4){0.f, 0.f, 0.f, 0.f};

    for (int dt = 0; dt < 4; ++dt) {
      __syncthreads();   // previous tile fully consumed
#pragma unroll
      for (int i = 0; i < 4; ++i) {
        const int rb = wv * 32 + i * 8;
        const size_t gox = (size_t)(row0 + rb + laneRow) * 512 + (size_t)(dt * 128 + srcswz);
        gload16(xhB + gox, (char*)lds_xh + rb * 128);
        gload16(xlB + gox, (char*)lds_xl + rb * 128);
        const size_t gow = (size_t)(ct * 128 + rb + laneRow) * 512 + (size_t)(dt * 128 + srcswz);
        gload16(whB + gow, (char*)lds_wh + rb * 128);
        gload16(wlB + gow, (char*)lds_wl + rb * 128);
      }
      __syncthreads();   // drains vmcnt + barrier

#pragma unroll
      for (int kh = 0; kh < 2; ++kh) {
        const int kb = kh * 64 + (lane >> 4) * 16;
        bf16x8 ah[4], al[4];
#pragma unroll
        for (int i = 0; i < 4; ++i) {
          const int r = wr * 64 + i * 16 + (lane & 15);
          const int off = r * 128 + (kb ^ ((r & 7) << 4));
          ah[i] = *(const bf16x8*)((const char*)lds_xh + off);
          al[i] = *(const bf16x8*)((const char*)lds_xl + off);
        }
#pragma unroll
        for (int j = 0; j < 4; ++j) {
          const int c = wc * 64 + j * 16 + (lane & 15);
          const int off = c * 128 + (kb ^ ((c & 7) << 4));
          bf16x8 bh = *(const bf16x8*)((const char*)lds_wh + off);
          bf16x8 bl = *(const bf16x8*)((const char*)lds_wl + off);
#pragma unroll
          for (int i = 0; i < 4; ++i) {
            acc[i][j] = __builtin_amdgcn_mfma_f32_16x16x32_bf16(ah[i], bh, acc[i][j], 0, 0, 0);
            acc[i][j] = __builtin_amdgcn_mfma_f32_16x16x32_bf16(ah[i], bl, acc[i][j], 0, 0, 0);
            acc[i][j] = __builtin_amdgcn_mfma_f32_16x16x32_bf16(al[i], bh, acc[i][j], 0, 0, 0);
          }
        }
      }
    }

    // top-2 update in e-space: e = sw - 2*dot  (sx drops out of per-row argmin)
#pragma unroll
    for (int j = 0; j < 4; ++j) {
      const int colbase = ct * 128 + wc * 64 + j * 16 + (lane & 15);
      const float swv = sws[colbase];
#pragma unroll
      for (int i = 0; i < 4; ++i)
#pragma unroll
        for (int q = 0; q < 4; ++q) {
          const int s = i * 4 + q;
          const float e = fmaf(-2.f, acc[i][j][q], swv);
          const bool c1 = e < b1[s];
          b2[s] = c1 ? b1[s] : fminf(b2[s], e);
          bi[s] = c1 ? colbase : bi[s];
          b1[s] = fminf(b1[s], e);
        }
    }
  }

  // merge across the 16 lanes sharing rows (lane&15 varies = different cols)
#pragma unroll
  for (int off = 1; off < 16; off <<= 1) {
#pragma unroll
    for (int s = 0; s < 16; ++s) {
      const float ob1 = __shfl_xor(b1[s], off);
      const float ob2 = __shfl_xor(b2[s], off);
      const int oi = __shfl_xor(bi[s], off);
      const float hi = fmaxf(b1[s], ob1);
      const bool take = ob1 < b1[s];
      b1[s] = fminf(b1[s], ob1);
      b2[s] = fminf(hi, fminf(b2[s], ob2));
      bi[s] = take ? oi : bi[s];
    }
  }
  if ((lane & 15) == 0) {
#pragma unroll
    for (int i = 0; i < 4; ++i)
#pragma unroll
      for (int q = 0; q < 4; ++q) {
        const int s = i * 4 + q;
        const int r = wr * 64 + i * 16 + (lane >> 4) * 4 + q;
        mrgB1[r][wc] = b1[s]; mrgB2[r][wc] = b2[s]; mrgI[r][wc] = bi[s];
      }
  }
  __syncthreads();
  if (t < TRM) {
    const float b1a = mrgB1[t][0], b1b = mrgB1[t][1];
    const float b2a = mrgB2[t][0], b2b = mrgB2[t][1];
    const bool take = b1b < b1a;
    const float b1f = fminf(b1a, b1b);
    const float b2f = fminf(fmaxf(b1a, b1b), fminf(b2a, b2b));
    const int idxf = take ? mrgI[t][1] : mrgI[t][0];
    const int grow = row0 + t;
    idxOut[grow] = idxf;
    idxOutF[grow] = (float)idxf;
    const bool flag = (b2f - b1f) < REPAIR_T;
    unsigned long long m = __ballot(flag);
    int base2 = 0;
    if ((t & 63) == 0) base2 = atomicAdd(flagCnt, __popcll(m));
    base2 = __shfl(base2, 0);
    if (flag) flagList[base2 + __popcll(m & ((1ull << (t & 63)) - 1ull))] = grow;
  }
}

// ========== fused: exact repair of flagged rows + codebook compactness ==========
// blocks [0,1024): repair; blocks [1024,2048): compact row i = blockIdx-1024
#define RPB 8
__global__ __launch_bounds__(256) void vq_repair_compact(
    const float* __restrict__ x, const float* __restrict__ w,
    const float* __restrict__ sw,
    const int* __restrict__ flagCnt, const int* __restrict__ flagList,
    int* __restrict__ idxOut, float* __restrict__ idxOutF,
    float* __restrict__ partialP) {
  const int t = threadIdx.x;
  if (blockIdx.x >= 1024) {
    // ---- compactness ----
    const int i = blockIdx.x - 1024;
    __shared__ float wi[DDIM];
    wi[t] = w[(size_t)i * DDIM + t];
    __syncthreads();
    float swi = sw[i];
    double s = 0.0;
    for (int j = i + 1 + t; j < KCODES; j += 256) {
      const float4* wj = (const float4*)(w + (size_t)j * DDIM);
      const float4* wi4 = (const float4*)wi;
      float acc = 0.f;
#pragma unroll 8
      for (int d4 = 0; d4 < DDIM / 4; ++d4) {
        float4 a = wi4[d4];
        float4 b = wj[d4];
        acc += a.x * b.x + a.y * b.y + a.z * b.z + a.w * b.w;
      }
      float pd2 = (swi + sw[j]) - 2.0f * acc;
      s += (double)sqrtf(fmaxf(pd2, 1e-12f));
    }
    for (int off = 32; off > 0; off >>= 1) s += __shfl_down(s, off);
    __shared__ double redc[4];
    if ((t & 63) == 0) redc[t >> 6] = s;
    __syncthreads();
    if (t == 0)
      partialP[i] = (float)(redc[0] + redc[1] + redc[2] + redc[3]);
    return;
  }
  // ---- repair ----
  __shared__ float xrow[RPB][DDIM];
  __shared__ float sxsh[RPB];
  __shared__ float rd[RPB][256];
  __shared__ int ri[RPB][256];
  const int cnt = flagCnt[0];
  for (int base = blockIdx.x * RPB; base < cnt; base += 1024 * RPB) {
    const int nr = min(RPB, cnt - base);
    int rowIdx[RPB];
#pragma unroll
    for (int r = 0; r < RPB; ++r)
      rowIdx[r] = flagList[base + ((r < nr) ? r : 0)];  // clamp padded slots (base < cnt)
    __syncthreads();
    for (int r = 0; r < nr; ++r)
      xrow[r][t] = x[(size_t)rowIdx[r] * DDIM + t];
    __syncthreads();
    // exact sx for this row: numpy pairwise order, no FMA
    if (t < nr) {
#pragma clang fp contract(off)
      float halves[2];
#pragma unroll
      for (int h = 0; h < 2; ++h) {
        const float* p = &xrow[t][h * 128];
        float acc[8];
#pragma unroll
        for (int j = 0; j < 8; ++j) { float v = p[j]; acc[j] = v * v; }
        for (int i = 8; i < 128; i += 8) {
#pragma unroll
          for (int j = 0; j < 8; ++j) { float v = p[i + j]; float e = v * v; acc[j] = acc[j] + e; }
        }
        halves[h] = ((acc[0] + acc[1]) + (acc[2] + acc[3])) + ((acc[4] + acc[5]) + (acc[6] + acc[7]));
      }
      sxsh[t] = halves[0] + halves[1];
    }
    __syncthreads();
    float bD[RPB]; int bI[RPB];
#pragma unroll
    for (int r = 0; r < RPB; ++r) { bD[r] = 3.4e38f; bI[r] = 0x7fffffff; }
    for (int g = 0; g < 4; ++g) {
      const int c = g * 256 + t;
      const float4* wrp = (const float4*)(w + (size_t)c * DDIM);
      float acc[RPB];
#pragma unroll
      for (int r = 0; r < RPB; ++r) acc[r] = 0.f;
      for (int d4 = 0; d4 < DDIM / 4; ++d4) {
        const float4 wv = wrp[d4];
#pragma unroll
        for (int e = 0; e < 4; ++e) {
          const float wvx = (e == 0) ? wv.x : (e == 1) ? wv.y : (e == 2) ? wv.z : wv.w;
#pragma unroll
          for (int r = 0; r < RPB; ++r) acc[r] = fmaf(xrow[r][d4 * 4 + e], wvx, acc[r]);
        }
      }
      const float swc = sw[c];
#pragma unroll
      for (int r = 0; r < RPB; ++r) {
        // dist = fl(fl(sx+sw) - 2*dot); g ascending => lowest code wins ties
        const float tt = sxsh[r] + swc;
        const float dist = tt - 2.0f * acc[r];
        if (dist < bD[r]) { bD[r] = dist; bI[r] = c; }
      }
    }
#pragma unroll
    for (int r = 0; r < RPB; ++r) { rd[r][t] = bD[r]; ri[r][t] = bI[r]; }
    __syncthreads();
    for (int s2 = 128; s2 > 0; s2 >>= 1) {
      if (t < s2) {
#pragma unroll
        for (int r = 0; r < RPB; ++r) {
          const float od = rd[r][t + s2]; const int oi = ri[r][t + s2];
          if (od < rd[r][t] || (od == rd[r][t] && oi < ri[r][t])) { rd[r][t] = od; ri[r][t] = oi; }
        }
      }
      __syncthreads();
    }
    if (t < nr) {
      const int row = rowIdx[t];
      idxOut[row] = ri[t][0];
      idxOutF[row] = (float)ri[t][0];
    }
    __syncthreads();
  }
}

// ====== gather + straight-through out + qloss partial + histogram ======
__global__ __launch_bounds__(256) void vq_quantize(const float* __restrict__ x,
                                                   const float* __restrict__ w,
                                                   const int* __restrict__ idxArr,
                                                   float* __restrict__ qout,
                                                   int* __restrict__ counts,
                                                   float* __restrict__ partialQ) {
  const int wave = threadIdx.x >> 6;
  const int lane = threadIdx.x & 63;
  const int base = blockIdx.x * 64 + wave * 16;
  float s = 0.f;
#pragma unroll 4
  for (int r = 0; r < 16; ++r) {
    const int row = base + r;
    const int idx = idxArr[row];
    float4 xv = ((const float4*)(x + (size_t)row * DDIM))[lane];
    float4 qv = ((const float4*)(w + (size_t)idx * DDIM))[lane];
    float dx = qv.x - xv.x, dy = qv.y - xv.y, dz = qv.z - xv.z, dw = qv.w - xv.w;
    float4 o;
    o.x = xv.x + dx; o.y = xv.y + dy; o.z = xv.z + dz; o.w = xv.w + dw;
    ((float4*)(qout + (size_t)row * DDIM))[lane] = o;
    s += dx * dx + dy * dy + dz * dz + dw * dw;
    if (lane == 0) atomicAdd(&counts[idx], 1);
  }
  double d = s;
  for (int off = 32; off > 0; off >>= 1) d += __shfl_down(d, off);
  __shared__ double red[4];
  if (lane == 0) red[wave] = d;
  __syncthreads();
  if (threadIdx.x == 0)
    partialQ[blockIdx.x] = (float)(red[0] + red[1] + red[2] + red[3]);
}

// ========== finalize ==========
__global__ __launch_bounds__(1024) void vq_final(const float* __restrict__ partialQ,
                                                 const float* __restrict__ partialP,
                                                 const int* __restrict__ counts,
                                                 float* __restrict__ out) {
  const int t = threadIdx.x;
  const int lane = t & 63, wave = t >> 6;
  double q = (double)partialQ[t];
  double p = (double)partialP[t];
  double u = (double)fabsf((float)counts[t] - 64.0f);
  for (int off = 32; off > 0; off >>= 1) {
    q += __shfl_down(q, off);
    p += __shfl_down(p, off);
    u += __shfl_down(u, off);
  }
  __shared__ double redQ[16], redP[16], redU[16];
  if (lane == 0) { redQ[wave] = q; redP[wave] = p; redU[wave] = u; }
  __syncthreads();
  if (t == 0) {
    double sq = 0, sp = 0, su = 0;
    for (int j = 0; j < 16; ++j) { sq += redQ[j]; sp += redP[j]; su += redU[j]; }
    float m = (float)(sq / 16777216.0);
    out[ND_TOT] = m + 0.25f * m;
    out[ND_TOT + 1] = (float)(su / 1024.0);
    out[ND_TOT + 2] = (float)(2.0 * sp / 523776.0);
  }
}

extern "C" void kernel_launch(void* const* d_in, const int* in_sizes, int n_in,
                              void* d_out, int out_size, void* d_ws, size_t ws_size,
                              hipStream_t stream) {
  const float* x = (const float*)d_in[0];
  const float* w = (const float*)d_in[1];
  float* out = (float*)d_out;

  char* ws = (char*)d_ws;
  int* wsIdx    = (int*)(ws + WS_IDX);
  int* counts   = (int*)(ws + WS_COUNTS);
  float* swv    = (float*)(ws + WS_SW);
  float* partQ  = (float*)(ws + WS_PARTQ);
  float* partP  = (float*)(ws + WS_PARTP);
  int* flagCnt  = (int*)(ws + WS_FLAGCNT);
  int* flagList = (int*)(ws + WS_FLAGLIST);
  unsigned short* whS = (unsigned short*)(ws + WS_WH);
  unsigned short* wlS = (unsigned short*)(ws + WS_WL);

  // bf16 splits of x live in the quantized-output region (overwritten by vq_quantize later)
  unsigned short* xhS = (unsigned short*)d_out;
  unsigned short* xlS = xhS + (size_t)ND_TOT;

  vq_prep<<<2052, 256, 0, stream>>>(x, w, xhS, xlS, swv, whS, wlS, counts, flagCnt);
  vq_argmin_mfma<<<NROWS / TRM, 256, 0, stream>>>(xhS, xlS, whS, wlS, swv,
                                                  wsIdx, out + ND_TOT + 3, flagCnt, flagList);
  vq_repair_compact<<<2048, 256, 0, stream>>>(x, w, swv, flagCnt, flagList,
                                              wsIdx, out + ND_TOT + 3, partP);
  vq_quantize<<<1024, 256, 0, stream>>>(x, w, wsIdx, out, counts, partQ);
  vq_final<<<1, 1024, 0, stream>>>(partQ, partP, counts, out);
}

// Round 11
// 264.777 us; speedup vs baseline: 2.6285x; 1.3025x over previous
//
#include <hip/hip_runtime.h>
#include <math.h>

#define NROWS 65536
#define KCODES 1024
#define DDIM 256
#define ND_TOT (NROWS * DDIM)

// ---------- ws layout (bytes) ----------
#define WS_IDX      0         // int idx[N]          256KB
#define WS_COUNTS   262144    // int counts[K]       4KB
#define WS_SW       266240    // float sw[K]         4KB
#define WS_PARTQ    532480    // float partQ[1024]   4KB
#define WS_PARTP    536576    // float partP[1024]   4KB
#define WS_FLAGCNT  540672    // int                 (256B slot)
#define WS_FLAGLIST 540928    // int flagList[N]     256KB
#define WS_WH       803072    // ushort wh[K*256]    512KB
#define WS_WL       1327360   // ushort wl[K*256]    512KB

typedef float f32x4 __attribute__((ext_vector_type(4)));
typedef short bf16x8 __attribute__((ext_vector_type(8)));

__device__ inline unsigned short f2bf(float f) {
  unsigned u = __float_as_uint(f);
  u += 0x7FFFu + ((u >> 16) & 1u);   // RNE to bf16
  return (unsigned short)(u >> 16);
}
__device__ inline float bf2f(unsigned short h) {
  return __uint_as_float(((unsigned)h) << 16);
}

__device__ inline void gload16(const void* g, void* l) {
  __builtin_amdgcn_global_load_lds((const __attribute__((address_space(1))) void*)g,
                                   (__attribute__((address_space(3))) void*)l, 16, 0, 0);
}

// ========== fused prep ==========
// blocks [0,2048):    x bf16-split, 4 groups of 8 floats per thread, loads batched (MLP)
//                     block 0 additionally zeroes counts+flagCnt
// blocks [2048,2304): w prep, 4 rows per block (one row per wave): coalesced split +
//                     exact numpy-pairwise sw via lane-parallel acc chains + shuffle tree
__global__ __launch_bounds__(256) void vq_prep(const float* __restrict__ x,
                                               const float* __restrict__ w,
                                               unsigned short* __restrict__ xh,
                                               unsigned short* __restrict__ xl,
                                               float* __restrict__ sw,
                                               unsigned short* __restrict__ wh,
                                               unsigned short* __restrict__ wl,
                                               int* __restrict__ counts,
                                               int* __restrict__ flagCnt) {
#pragma clang fp contract(off)
  const int b = blockIdx.x;
  const int t = threadIdx.x;
  if (b >= 2048) {
    const int lane = t & 63, wv = t >> 6;
    const int row = (b - 2048) * 4 + wv;           // 256 blocks x 4 rows = 1024
    const float* src = w + (size_t)row * DDIM;
    float4 v4 = *(const float4*)&src[lane * 4];    // full row per wave, coalesced
    float fv[4] = {v4.x, v4.y, v4.z, v4.w};
    union { unsigned short us[4]; uint2 v; } ph, pl;
#pragma unroll
    for (int e = 0; e < 4; ++e) {
      unsigned short h = f2bf(fv[e]);
      ph.us[e] = h;
      pl.us[e] = f2bf(fv[e] - bf2f(h));
    }
    *(uint2*)&wh[(size_t)row * DDIM + lane * 4] = ph.v;
    *(uint2*)&wl[(size_t)row * DDIM + lane * 4] = pl.v;
    // exact sw: numpy pairwise_sum(256) = two 128-halves x 8 accumulators.
    // lane<16: half=(lane>>3), accumulator j=(lane&7); serial k-chain keeps ref order.
    float acc = 0.f;
    if (lane < 16) {
      const float* p = src + ((lane >> 3) & 1) * 128 + (lane & 7);
      float v = p[0];
      acc = v * v;
      for (int k = 1; k < 16; ++k) { float vv = p[k * 8]; float e = vv * vv; acc = acc + e; }
    }
    // tree combine in reference association order ((a0+a1)+(a2+a3))+((a4+a5)+(a6+a7))
    acc = acc + __shfl_xor(acc, 1);
    acc = acc + __shfl_xor(acc, 2);
    acc = acc + __shfl_xor(acc, 4);
    const float hb = __shfl(acc, 8);               // half-1 total sits at lane 8
    if (lane == 0) sw[row] = acc + hb;
    return;
  }
  if (b == 0) {
#pragma unroll
    for (int j = 0; j < 4; ++j) counts[j * 256 + t] = 0;
    if (t == 0) flagCnt[0] = 0;
  }
  // ---- x split: batch all 8 loads before converting (4x outstanding loads/wave) ----
  const size_t tid = (size_t)b * 256 + t;
  float4 a[4], c[4];
#pragma unroll
  for (int g = 0; g < 4; ++g) {
    const size_t e = ((size_t)g * 524288 + tid) * 8;
    a[g] = *(const float4*)&x[e];
    c[g] = *(const float4*)&x[e + 4];
  }
#pragma unroll
  for (int g = 0; g < 4; ++g) {
    const size_t e = ((size_t)g * 524288 + tid) * 8;
    float fv[8] = {a[g].x, a[g].y, a[g].z, a[g].w, c[g].x, c[g].y, c[g].z, c[g].w};
    union { unsigned short us[8]; uint4 v; } ph, pl;
#pragma unroll
    for (int k = 0; k < 8; ++k) {
      unsigned short h = f2bf(fv[k]);
      ph.us[k] = h;
      pl.us[k] = f2bf(fv[k] - bf2f(h));   // exact in fp32
    }
    *(uint4*)&xh[e] = ph.v;
    *(uint4*)&xl[e] = pl.v;
  }
}

// ========== MFMA split-bf16 distance + top2 argmin (R6 structure, proven 111us) ==========
#define TRM 128
#define BKM 64
// Flag threshold: hard bound for a reference-order flip is
//   approx-e error (<=~6e-6) + reference rounding reorder width (~6.1e-5).
// Total ~7.3e-5; T=1.5e-4 keeps 2x margin.
#define REPAIR_T 1.5e-4f

__global__ __launch_bounds__(256, 2) void vq_argmin_mfma(
    const unsigned short* __restrict__ xh, const unsigned short* __restrict__ xl,
    const unsigned short* __restrict__ wh, const unsigned short* __restrict__ wl,
    const float* __restrict__ sw,
    int* __restrict__ idxOut, float* __restrict__ idxOutF,
    int* __restrict__ flagCnt, int* __restrict__ flagList) {
  __shared__ __align__(16) unsigned short lds_xh[TRM * BKM];  // 16KB each, XOR-swizzled
  __shared__ __align__(16) unsigned short lds_xl[TRM * BKM];
  __shared__ __align__(16) unsigned short lds_wh[TRM * BKM];
  __shared__ __align__(16) unsigned short lds_wl[TRM * BKM];
  __shared__ __align__(16) float sws[KCODES];
  __shared__ float mrgB1[TRM][2];
  __shared__ float mrgB2[TRM][2];
  __shared__ int   mrgI[TRM][2];

  const int t = threadIdx.x;
  const int lane = t & 63, wv = t >> 6;
  const int wr = wv >> 1, wc = wv & 1;     // wave quadrant: rows 64*wr, cols 64*wc
  const int row0 = blockIdx.x * TRM;

  { f32x4 v = ((const f32x4*)sw)[t]; ((f32x4*)sws)[t] = v; }  // 1024 floats

  const int laneRow = lane >> 3;                                  // 0..7
  const int srcswz = ((lane & 7) * 16) ^ ((laneRow & 7) << 4);    // pre-swizzled source chunk
  const char* xhB = (const char*)xh;
  const char* xlB = (const char*)xl;
  const char* whB = (const char*)wh;
  const char* wlB = (const char*)wl;

  float b1[16], b2[16];
  int bi[16];
#pragma unroll
  for (int s = 0; s < 16; ++s) { b1[s] = 3.4e38f; b2[s] = 3.4e38f; bi[s] = 0; }

  for (int ct = 0; ct < KCODES / TRM; ++ct) {
    f32x4 acc[4][4];
#pragma unroll
    for (int i = 0; i < 4; ++i)
#pragma unroll
      for (int j = 0; j < 4; ++j) acc[i][j] = (f32x4){0.f, 0.f, 0.f, 0.f};

    for (int dt = 0; dt < 4; ++dt) {
      __syncthreads();   // previous tile fully consumed
#pragma unroll
      for (int i = 0; i < 4; ++i) {
        const int rb = wv * 32 + i * 8;
        const size_t gox = (size_t)(row0 + rb + laneRow) * 512 + (size_t)(dt * 128 + srcswz);
        gload16(xhB + gox, (char*)lds_xh + rb * 128);
        gload16(xlB + gox, (char*)lds_xl + rb * 128);
        const size_t gow = (size_t)(ct * 128 + rb + laneRow) * 512 + (size_t)(dt * 128 + srcswz);
        gload16(whB + gow, (char*)lds_wh + rb * 128);
        gload16(wlB + gow, (char*)lds_wl + rb * 128);
      }
      __syncthreads();   // drains vmcnt + barrier

#pragma unroll
      for (int kh = 0; kh < 2; ++kh) {
        const int kb = kh * 64 + (lane >> 4) * 16;
        bf16x8 ah[4], al[4];
#pragma unroll
        for (int i = 0; i < 4; ++i) {
          const int r = wr * 64 + i * 16 + (lane & 15);
          const int off = r * 128 + (kb ^ ((r & 7) << 4));
          ah[i] = *(const bf16x8*)((const char*)lds_xh + off);
          al[i] = *(const bf16x8*)((const char*)lds_xl + off);
        }
#pragma unroll
        for (int j = 0; j < 4; ++j) {
          const int c = wc * 64 + j * 16 + (lane & 15);
          const int off = c * 128 + (kb ^ ((c & 7) << 4));
          bf16x8 bh = *(const bf16x8*)((const char*)lds_wh + off);
          bf16x8 bl = *(const bf16x8*)((const char*)lds_wl + off);
#pragma unroll
          for (int i = 0; i < 4; ++i) {
            acc[i][j] = __builtin_amdgcn_mfma_f32_16x16x32_bf16(ah[i], bh, acc[i][j], 0, 0, 0);
            acc[i][j] = __builtin_amdgcn_mfma_f32_16x16x32_bf16(ah[i], bl, acc[i][j], 0, 0, 0);
            acc[i][j] = __builtin_amdgcn_mfma_f32_16x16x32_bf16(al[i], bh, acc[i][j], 0, 0, 0);
          }
        }
      }
    }

    // top-2 update in e-space: e = sw - 2*dot  (sx drops out of per-row argmin)
#pragma unroll
    for (int j = 0; j < 4; ++j) {
      const int colbase = ct * 128 + wc * 64 + j * 16 + (lane & 15);
      const float swv = sws[colbase];
#pragma unroll
      for (int i = 0; i < 4; ++i)
#pragma unroll
        for (int q = 0; q < 4; ++q) {
          const int s = i * 4 + q;
          const float e = fmaf(-2.f, acc[i][j][q], swv);
          const bool c1 = e < b1[s];
          b2[s] = c1 ? b1[s] : fminf(b2[s], e);
          bi[s] = c1 ? colbase : bi[s];
          b1[s] = fminf(b1[s], e);
        }
    }
  }

  // merge across the 16 lanes sharing rows (lane&15 varies = different cols)
#pragma unroll
  for (int off = 1; off < 16; off <<= 1) {
#pragma unroll
    for (int s = 0; s < 16; ++s) {
      const float ob1 = __shfl_xor(b1[s], off);
      const float ob2 = __shfl_xor(b2[s], off);
      const int oi = __shfl_xor(bi[s], off);
      const float hi = fmaxf(b1[s], ob1);
      const bool take = ob1 < b1[s];
      b1[s] = fminf(b1[s], ob1);
      b2[s] = fminf(hi, fminf(b2[s], ob2));
      bi[s] = take ? oi : bi[s];
    }
  }
  if ((lane & 15) == 0) {
#pragma unroll
    for (int i = 0; i < 4; ++i)
#pragma unroll
      for (int q = 0; q < 4; ++q) {
        const int s = i * 4 + q;
        const int r = wr * 64 + i * 16 + (lane >> 4) * 4 + q;
        mrgB1[r][wc] = b1[s]; mrgB2[r][wc] = b2[s]; mrgI[r][wc] = bi[s];
      }
  }
  __syncthreads();
  if (t < TRM) {
    const float b1a = mrgB1[t][0], b1b = mrgB1[t][1];
    const float b2a = mrgB2[t][0], b2b = mrgB2[t][1];
    const bool take = b1b < b1a;
    const float b1f = fminf(b1a, b1b);
    const float b2f = fminf(fmaxf(b1a, b1b), fminf(b2a, b2b));
    const int idxf = take ? mrgI[t][1] : mrgI[t][0];
    const int grow = row0 + t;
    idxOut[grow] = idxf;
    idxOutF[grow] = (float)idxf;
    const bool flag = (b2f - b1f) < REPAIR_T;
    unsigned long long m = __ballot(flag);
    int base2 = 0;
    if ((t & 63) == 0) base2 = atomicAdd(flagCnt, __popcll(m));
    base2 = __shfl(base2, 0);
    if (flag) flagList[base2 + __popcll(m & ((1ull << (t & 63)) - 1ull))] = grow;
  }
}

// ========== fused: exact repair of flagged rows + codebook compactness ==========
// blocks [0,1024): repair; blocks [1024,2048): compact row i = blockIdx-1024
#define RPB 8
__global__ __launch_bounds__(256) void vq_repair_compact(
    const float* __restrict__ x, const float* __restrict__ w,
    const float* __restrict__ sw,
    const int* __restrict__ flagCnt, const int* __restrict__ flagList,
    int* __restrict__ idxOut, float* __restrict__ idxOutF,
    float* __restrict__ partialP) {
  const int t = threadIdx.x;
  if (blockIdx.x >= 1024) {
    // ---- compactness ----
    const int i = blockIdx.x - 1024;
    __shared__ float wi[DDIM];
    wi[t] = w[(size_t)i * DDIM + t];
    __syncthreads();
    float swi = sw[i];
    double s = 0.0;
    for (int j = i + 1 + t; j < KCODES; j += 256) {
      const float4* wj = (const float4*)(w + (size_t)j * DDIM);
      const float4* wi4 = (const float4*)wi;
      float acc = 0.f;
#pragma unroll 8
      for (int d4 = 0; d4 < DDIM / 4; ++d4) {
        float4 a = wi4[d4];
        float4 b = wj[d4];
        acc += a.x * b.x + a.y * b.y + a.z * b.z + a.w * b.w;
      }
      float pd2 = (swi + sw[j]) - 2.0f * acc;
      s += (double)sqrtf(fmaxf(pd2, 1e-12f));
    }
    for (int off = 32; off > 0; off >>= 1) s += __shfl_down(s, off);
    __shared__ double redc[4];
    if ((t & 63) == 0) redc[t >> 6] = s;
    __syncthreads();
    if (t == 0)
      partialP[i] = (float)(redc[0] + redc[1] + redc[2] + redc[3]);
    return;
  }
  // ---- repair ----
  __shared__ float xrow[RPB][DDIM];
  __shared__ float sxsh[RPB];
  __shared__ float rd[RPB][256];
  __shared__ int ri[RPB][256];
  const int cnt = flagCnt[0];
  for (int base = blockIdx.x * RPB; base < cnt; base += 1024 * RPB) {
    const int nr = min(RPB, cnt - base);
    int rowIdx[RPB];
#pragma unroll
    for (int r = 0; r < RPB; ++r)
      rowIdx[r] = flagList[base + ((r < nr) ? r : 0)];  // clamp padded slots (base < cnt)
    __syncthreads();
    for (int r = 0; r < nr; ++r)
      xrow[r][t] = x[(size_t)rowIdx[r] * DDIM + t];
    __syncthreads();
    // exact sx for this row: numpy pairwise order, no FMA
    if (t < nr) {
#pragma clang fp contract(off)
      float halves[2];
#pragma unroll
      for (int h = 0; h < 2; ++h) {
        const float* p = &xrow[t][h * 128];
        float acc[8];
#pragma unroll
        for (int j = 0; j < 8; ++j) { float v = p[j]; acc[j] = v * v; }
        for (int i = 8; i < 128; i += 8) {
#pragma unroll
          for (int j = 0; j < 8; ++j) { float v = p[i + j]; float e = v * v; acc[j] = acc[j] + e; }
        }
        halves[h] = ((acc[0] + acc[1]) + (acc[2] + acc[3])) + ((acc[4] + acc[5]) + (acc[6] + acc[7]));
      }
      sxsh[t] = halves[0] + halves[1];
    }
    __syncthreads();
    float bD[RPB]; int bI[RPB];
#pragma unroll
    for (int r = 0; r < RPB; ++r) { bD[r] = 3.4e38f; bI[r] = 0x7fffffff; }
    for (int g = 0; g < 4; ++g) {
      const int c = g * 256 + t;
      const float4* wrp = (const float4*)(w + (size_t)c * DDIM);
      float acc[RPB];
#pragma unroll
      for (int r = 0; r < RPB; ++r) acc[r] = 0.f;
      for (int d4 = 0; d4 < DDIM / 4; ++d4) {
        const float4 wv = wrp[d4];
#pragma unroll
        for (int e = 0; e < 4; ++e) {
          const float wvx = (e == 0) ? wv.x : (e == 1) ? wv.y : (e == 2) ? wv.z : wv.w;
#pragma unroll
          for (int r = 0; r < RPB; ++r) acc[r] = fmaf(xrow[r][d4 * 4 + e], wvx, acc[r]);
        }
      }
      const float swc = sw[c];
#pragma unroll
      for (int r = 0; r < RPB; ++r) {
        // dist = fl(fl(sx+sw) - 2*dot); g ascending => lowest code wins ties
        const float tt = sxsh[r] + swc;
        const float dist = tt - 2.0f * acc[r];
        if (dist < bD[r]) { bD[r] = dist; bI[r] = c; }
      }
    }
#pragma unroll
    for (int r = 0; r < RPB; ++r) { rd[r][t] = bD[r]; ri[r][t] = bI[r]; }
    __syncthreads();
    for (int s2 = 128; s2 > 0; s2 >>= 1) {
      if (t < s2) {
#pragma unroll
        for (int r = 0; r < RPB; ++r) {
          const float od = rd[r][t + s2]; const int oi = ri[r][t + s2];
          if (od < rd[r][t] || (od == rd[r][t] && oi < ri[r][t])) { rd[r][t] = od; ri[r][t] = oi; }
        }
      }
      __syncthreads();
    }
    if (t < nr) {
      const int row = rowIdx[t];
      idxOut[row] = ri[t][0];
      idxOutF[row] = (float)ri[t][0];
    }
    __syncthreads();
  }
}

// ====== gather + straight-through out + qloss partial + histogram ======
__global__ __launch_bounds__(256) void vq_quantize(const float* __restrict__ x,
                                                   const float* __restrict__ w,
                                                   const int* __restrict__ idxArr,
                                                   float* __restrict__ qout,
                                                   int* __restrict__ counts,
                                                   float* __restrict__ partialQ) {
  const int wave = threadIdx.x >> 6;
  const int lane = threadIdx.x & 63;
  const int base = blockIdx.x * 64 + wave * 16;
  float s = 0.f;
#pragma unroll 4
  for (int r = 0; r < 16; ++r) {
    const int row = base + r;
    const int idx = idxArr[row];
    float4 xv = ((const float4*)(x + (size_t)row * DDIM))[lane];
    float4 qv = ((const float4*)(w + (size_t)idx * DDIM))[lane];
    float dx = qv.x - xv.x, dy = qv.y - xv.y, dz = qv.z - xv.z, dw = qv.w - xv.w;
    float4 o;
    o.x = xv.x + dx; o.y = xv.y + dy; o.z = xv.z + dz; o.w = xv.w + dw;
    ((float4*)(qout + (size_t)row * DDIM))[lane] = o;
    s += dx * dx + dy * dy + dz * dz + dw * dw;
    if (lane == 0) atomicAdd(&counts[idx], 1);
  }
  double d = s;
  for (int off = 32; off > 0; off >>= 1) d += __shfl_down(d, off);
  __shared__ double red[4];
  if (lane == 0) red[wave] = d;
  __syncthreads();
  if (threadIdx.x == 0)
    partialQ[blockIdx.x] = (float)(red[0] + red[1] + red[2] + red[3]);
}

// ========== finalize ==========
__global__ __launch_bounds__(1024) void vq_final(const float* __restrict__ partialQ,
                                                 const float* __restrict__ partialP,
                                                 const int* __restrict__ counts,
                                                 float* __restrict__ out) {
  const int t = threadIdx.x;
  const int lane = t & 63, wave = t >> 6;
  double q = (double)partialQ[t];
  double p = (double)partialP[t];
  double u = (double)fabsf((float)counts[t] - 64.0f);
  for (int off = 32; off > 0; off >>= 1) {
    q += __shfl_down(q, off);
    p += __shfl_down(p, off);
    u += __shfl_down(u, off);
  }
  __shared__ double redQ[16], redP[16], redU[16];
  if (lane == 0) { redQ[wave] = q; redP[wave] = p; redU[wave] = u; }
  __syncthreads();
  if (t == 0) {
    double sq = 0, sp = 0, su = 0;
    for (int j = 0; j < 16; ++j) { sq += redQ[j]; sp += redP[j]; su += redU[j]; }
    float m = (float)(sq / 16777216.0);
    out[ND_TOT] = m + 0.25f * m;
    out[ND_TOT + 1] = (float)(su / 1024.0);
    out[ND_TOT + 2] = (float)(2.0 * sp / 523776.0);
  }
}

extern "C" void kernel_launch(void* const* d_in, const int* in_sizes, int n_in,
                              void* d_out, int out_size, void* d_ws, size_t ws_size,
                              hipStream_t stream) {
  const float* x = (const float*)d_in[0];
  const float* w = (const float*)d_in[1];
  float* out = (float*)d_out;

  char* ws = (char*)d_ws;
  int* wsIdx    = (int*)(ws + WS_IDX);
  int* counts   = (int*)(ws + WS_COUNTS);
  float* swv    = (float*)(ws + WS_SW);
  float* partQ  = (float*)(ws + WS_PARTQ);
  float* partP  = (float*)(ws + WS_PARTP);
  int* flagCnt  = (int*)(ws + WS_FLAGCNT);
  int* flagList = (int*)(ws + WS_FLAGLIST);
  unsigned short* whS = (unsigned short*)(ws + WS_WH);
  unsigned short* wlS = (unsigned short*)(ws + WS_WL);

  // bf16 splits of x live in the quantized-output region (overwritten by vq_quantize later)
  unsigned short* xhS = (unsigned short*)d_out;
  unsigned short* xlS = xhS + (size_t)ND_TOT;

  vq_prep<<<2304, 256, 0, stream>>>(x, w, xhS, xlS, swv, whS, wlS, counts, flagCnt);
  vq_argmin_mfma<<<NROWS / TRM, 256, 0, stream>>>(xhS, xlS, whS, wlS, swv,
                                                  wsIdx, out + ND_TOT + 3, flagCnt, flagList);
  vq_repair_compact<<<2048, 256, 0, stream>>>(x, w, swv, flagCnt, flagList,
                                              wsIdx, out + ND_TOT + 3, partP);
  vq_quantize<<<1024, 256, 0, stream>>>(x, w, wsIdx, out, counts, partQ);
  vq_final<<<1, 1024, 0, stream>>>(partQ, partP, counts, out);
}